// Round 1
// baseline (264.722 us; speedup 1.0000x reference)
//
#include <hip/hip_runtime.h>

// Per-sample depthwise 7x7 cross-correlation, NHWC, SAME padding.
// inputs:  [B,H,W,C] fp32, kernels: [B,7,7,C] fp32, out: [B,H,W,C] fp32.
// out[b,y,x,c] = sum_{i,j} in[b, y+i-3, x+j-3, c] * ker[b,i,j,c]  (zero pad)

#define BB 32
#define HH 128
#define WW 128
#define CC 128
#define KH 7
#define KW 7

__global__ __launch_bounds__(256, 4) void crossconv_kernel(
    const float* __restrict__ in,
    const float* __restrict__ ker,
    float* __restrict__ out)
{
    const int tid = threadIdx.x;
    const int c  = tid & (CC - 1);   // 0..127, contiguous across lanes -> coalesced
    const int xo = tid >> 7;         // 0..1 (two x positions per block)
    const int bx = blockIdx.x;
    const int xp = bx & 63;          // x-pair index 0..63
    const int b  = bx >> 6;          // sample 0..31
    const int x  = xp * 2 + xo;

    // Hoist all 49 weights for (b, :, :, c) into registers.
    float w[KH][KW];
    {
        const float* kb = ker + ((size_t)b * KH * KW) * CC + c;
        #pragma unroll
        for (int i = 0; i < KH; ++i)
            #pragma unroll
            for (int j = 0; j < KW; ++j)
                w[i][j] = kb[(i * KW + j) * CC];
    }

    const float* ib = in  + ((size_t)b * HH * WW) * CC;
    float*       ob = out + ((size_t)b * HH * WW) * CC;

    // Precompute x-tap offsets & validity (wave-uniform: x is uniform per wave).
    bool xvalid[KW];
    int  xoff[KW];
    #pragma unroll
    for (int j = 0; j < KW; ++j) {
        int xx = x + j - 3;
        xvalid[j] = (xx >= 0) && (xx < WW);
        xoff[j]   = xx * CC + c;
    }

    // Sliding accumulator ring: acc[s] holds partial for output row y = yi-3+s.
    float acc[KH];
    #pragma unroll
    for (int i = 0; i < KH; ++i) acc[i] = 0.0f;

    for (int yi = 0; yi < HH + 3; ++yi) {
        float t[KW];
        if (yi < HH) {
            const float* row = ib + (size_t)yi * WW * CC;
            #pragma unroll
            for (int j = 0; j < KW; ++j)
                t[j] = xvalid[j] ? row[xoff[j]] : 0.0f;
        } else {
            #pragma unroll
            for (int j = 0; j < KW; ++j) t[j] = 0.0f;
        }

        // Input row yi feeds output y = yi-3+s with kernel row i = 6-s.
        #pragma unroll
        for (int i = 0; i < KH; ++i)
            #pragma unroll
            for (int j = 0; j < KW; ++j)
                acc[6 - i] = fmaf(w[i][j], t[j], acc[6 - i]);

        const int y = yi - 3;
        if (y >= 0)
            ob[((size_t)y * WW + x) * CC + c] = acc[0];

        // Shift ring down, open a fresh slot at the top.
        #pragma unroll
        for (int s = 0; s < KH - 1; ++s) acc[s] = acc[s + 1];
        acc[KH - 1] = 0.0f;
    }
}

extern "C" void kernel_launch(void* const* d_in, const int* in_sizes, int n_in,
                              void* d_out, int out_size, void* d_ws, size_t ws_size,
                              hipStream_t stream) {
    const float* in  = (const float*)d_in[0];
    const float* ker = (const float*)d_in[1];
    float*       out = (float*)d_out;

    const int grid = BB * (WW / 2);  // 2048 blocks
    crossconv_kernel<<<grid, 256, 0, stream>>>(in, ker, out);
}